// Round 1
// baseline (128.208 us; speedup 1.0000x reference)
//
#include <hip/hip_runtime.h>

#define N_ELEM 4194304
constexpr int BLOCKS  = 2048;
constexpr int THREADS = 256;

// Closed-form 2x2 symmetric spectral apply: f(A) = coef*(A - l1*I) + f(l1)*I
// with coef = (f(l2)-f(l1))/(l2-l1). All in fp32, mirroring the jnp reference.
__device__ __forceinline__ float elem_loss(float pa, float pb, float pc,
                                           float ma, float mb, float mc) {
    // ---- E = exp(pred) ----
    float mid  = 0.5f * (pa + pc);
    float hd   = 0.5f * (pa - pc);
    float disc = sqrtf(hd * hd + pb * pb);
    float l1 = mid - disc, l2 = mid + disc;
    float f1 = __expf(l1), f2 = __expf(l2);
    float coef = (f2 - f1) / fmaxf(l2 - l1, 1e-12f);
    float ea = coef * (pa - l1) + f1;
    float eb = coef * pb;
    float ec = coef * (pc - l1) + f1;

    // ---- T = E^{-1/2} ----
    mid  = 0.5f * (ea + ec);
    hd   = 0.5f * (ea - ec);
    disc = sqrtf(hd * hd + eb * eb);
    l1 = mid - disc; l2 = mid + disc;
    f1 = rsqrtf(l1); f2 = rsqrtf(l2);
    coef = (f2 - f1) / fmaxf(l2 - l1, 1e-12f);
    float ta = coef * (ea - l1) + f1;
    float tb = coef * eb;
    float tc = coef * (ec - l1) + f1;

    // ---- P = T * M * T  (all symmetric 2x2) ----
    float u00 = ma * ta + mb * tb;
    float u01 = ma * tb + mb * tc;
    float u10 = mb * ta + mc * tb;
    float u11 = mb * tb + mc * tc;
    float p00 = ta * u00 + tb * u10;
    float p01 = ta * u01 + tb * u11;
    float p11 = tb * u01 + tc * u11;

    // ---- S = log(P) ----
    mid  = 0.5f * (p00 + p11);
    hd   = 0.5f * (p00 - p11);
    disc = sqrtf(hd * hd + p01 * p01);
    l1 = mid - disc; l2 = mid + disc;
    f1 = __logf(l1); f2 = __logf(l2);
    coef = (f2 - f1) / fmaxf(l2 - l1, 1e-12f);
    float sa = coef * (p00 - l1) + f1;
    float sb = coef * p01;
    float sc = coef * (p11 - l1) + f1;

    return sa * sa + 2.0f * sb * sb + sc * sc;
}

__global__ __launch_bounds__(THREADS) void metric_loss_kernel(
        const float* __restrict__ pred,
        const float* __restrict__ act,
        float* __restrict__ out) {
    const float4* p4 = reinterpret_cast<const float4*>(pred);
    const float4* a4 = reinterpret_cast<const float4*>(act);

    float acc = 0.0f;
    const int nquad  = N_ELEM / 4;          // 4 rows = 3 float4s per input
    const int stride = BLOCKS * THREADS;
    for (int q = blockIdx.x * THREADS + threadIdx.x; q < nquad; q += stride) {
        float4 p0 = p4[3 * q + 0];
        float4 p1 = p4[3 * q + 1];
        float4 p2 = p4[3 * q + 2];
        float4 a0 = a4[3 * q + 0];
        float4 a1 = a4[3 * q + 1];
        float4 a2 = a4[3 * q + 2];
        acc += elem_loss(p0.x, p0.y, p0.z, a0.x, a0.y, a0.z);
        acc += elem_loss(p0.w, p1.x, p1.y, a0.w, a1.x, a1.y);
        acc += elem_loss(p1.z, p1.w, p2.x, a1.z, a1.w, a2.x);
        acc += elem_loss(p2.y, p2.z, p2.w, a2.y, a2.z, a2.w);
    }

    // wave-64 butterfly reduce
    #pragma unroll
    for (int off = 32; off; off >>= 1)
        acc += __shfl_down(acc, off, 64);

    __shared__ float s[THREADS / 64];
    const int lane = threadIdx.x & 63;
    const int wid  = threadIdx.x >> 6;
    if (lane == 0) s[wid] = acc;
    __syncthreads();
    if (threadIdx.x == 0) {
        float bsum = s[0] + s[1] + s[2] + s[3];
        atomicAdd(out, bsum * (1.0f / (float)N_ELEM));
    }
}

extern "C" void kernel_launch(void* const* d_in, const int* in_sizes, int n_in,
                              void* d_out, int out_size, void* d_ws, size_t ws_size,
                              hipStream_t stream) {
    const float* pred = (const float*)d_in[0];
    const float* act  = (const float*)d_in[1];
    float* out = (float*)d_out;

    // d_out is re-poisoned to 0xAA before every timed launch; zero it ourselves.
    hipMemsetAsync(out, 0, sizeof(float), stream);
    metric_loss_kernel<<<BLOCKS, THREADS, 0, stream>>>(pred, act, out);
}

// Round 11
// 127.048 us; speedup vs baseline: 1.0091x; 1.0091x over previous
//
#include <hip/hip_runtime.h>

#define N_ELEM 4194304
constexpr int BLOCKS  = 2048;
constexpr int THREADS = 256;
constexpr int NTHREADS_TOT = BLOCKS * THREADS;   // 524288
constexpr int NQUAD = N_ELEM / 4;                // 1048576 = 2 * NTHREADS_TOT

// Fast single-instruction approximations (~1 ulp of native tables).
// absmax headroom is enormous (R1 measured 0.0 vs threshold 4.06e-2); the
// final mean over 4.19M rows averages away per-element approx error.
__device__ __forceinline__ float fast_rcp(float x)  { return __builtin_amdgcn_rcpf(x); }
__device__ __forceinline__ float fast_sqrt(float x) { return __builtin_amdgcn_sqrtf(x); }
__device__ __forceinline__ float fast_rsq(float x)  { return __builtin_amdgcn_rsqf(x); }

// Closed-form 2x2 symmetric spectral apply: f(A) = coef*(A - l1*I) + f(l1)*I,
// coef = (f(l2)-f(l1))/(l2-l1). Mirrors the jnp reference in fp32.
__device__ __forceinline__ float elem_loss(float pa, float pb, float pc,
                                           float ma, float mb, float mc) {
    // ---- E = exp(pred) ----
    float mid  = 0.5f * (pa + pc);
    float hd   = 0.5f * (pa - pc);
    float disc = fast_sqrt(fmaf(hd, hd, pb * pb));
    float l1 = mid - disc, l2 = mid + disc;
    float f1 = __expf(l1), f2 = __expf(l2);
    float coef = (f2 - f1) * fast_rcp(fmaxf(l2 - l1, 1e-12f));
    float ea = fmaf(coef, pa - l1, f1);
    float eb = coef * pb;
    float ec = fmaf(coef, pc - l1, f1);

    // ---- T = E^{-1/2} ----
    mid  = 0.5f * (ea + ec);
    hd   = 0.5f * (ea - ec);
    disc = fast_sqrt(fmaf(hd, hd, eb * eb));
    l1 = mid - disc; l2 = mid + disc;
    f1 = fast_rsq(l1); f2 = fast_rsq(l2);
    coef = (f2 - f1) * fast_rcp(fmaxf(l2 - l1, 1e-12f));
    float ta = fmaf(coef, ea - l1, f1);
    float tb = coef * eb;
    float tc = fmaf(coef, ec - l1, f1);

    // ---- P = T * M * T ----
    float u00 = fmaf(ma, ta, mb * tb);
    float u01 = fmaf(ma, tb, mb * tc);
    float u10 = fmaf(mb, ta, mc * tb);
    float u11 = fmaf(mb, tb, mc * tc);
    float p00 = fmaf(ta, u00, tb * u10);
    float p01 = fmaf(ta, u01, tb * u11);
    float p11 = fmaf(tb, u01, tc * u11);

    // ---- S = log(P) ----
    mid  = 0.5f * (p00 + p11);
    hd   = 0.5f * (p00 - p11);
    disc = fast_sqrt(fmaf(hd, hd, p01 * p01));
    l1 = mid - disc; l2 = mid + disc;
    f1 = __logf(l1); f2 = __logf(l2);
    coef = (f2 - f1) * fast_rcp(fmaxf(l2 - l1, 1e-12f));
    float sa = fmaf(coef, p00 - l1, f1);
    float sb = coef * p01;
    float sc = fmaf(coef, p11 - l1, f1);

    return fmaf(sa, sa, fmaf(2.0f * sb, sb, sc * sc));
}

__device__ __forceinline__ float quad_loss(float4 p0, float4 p1, float4 p2,
                                           float4 a0, float4 a1, float4 a2) {
    float s = 0.0f;
    s += elem_loss(p0.x, p0.y, p0.z, a0.x, a0.y, a0.z);
    s += elem_loss(p0.w, p1.x, p1.y, a0.w, a1.x, a1.y);
    s += elem_loss(p1.z, p1.w, p2.x, a1.z, a1.w, a2.x);
    s += elem_loss(p2.y, p2.z, p2.w, a2.y, a2.z, a2.w);
    return s;
}

__global__ __launch_bounds__(THREADS) void metric_loss_kernel(
        const float* __restrict__ pred,
        const float* __restrict__ act,
        float* __restrict__ out) {
    const float4* p4 = reinterpret_cast<const float4*>(pred);
    const float4* a4 = reinterpret_cast<const float4*>(act);

    const int tid = blockIdx.x * THREADS + threadIdx.x;  // 0..524287
    const int q0  = tid;
    const int q1  = tid + NTHREADS_TOT;

    // Issue ALL 12 loads up front — max outstanding bytes per wave, one
    // vmcnt wait covered by the whole compute phase.
    float4 P0 = p4[3 * q0 + 0];
    float4 P1 = p4[3 * q0 + 1];
    float4 P2 = p4[3 * q0 + 2];
    float4 P3 = p4[3 * q1 + 0];
    float4 P4 = p4[3 * q1 + 1];
    float4 P5 = p4[3 * q1 + 2];
    float4 A0 = a4[3 * q0 + 0];
    float4 A1 = a4[3 * q0 + 1];
    float4 A2 = a4[3 * q0 + 2];
    float4 A3 = a4[3 * q1 + 0];
    float4 A4 = a4[3 * q1 + 1];
    float4 A5 = a4[3 * q1 + 2];

    float acc = quad_loss(P0, P1, P2, A0, A1, A2)
              + quad_loss(P3, P4, P5, A3, A4, A5);

    // wave-64 reduce
    #pragma unroll
    for (int off = 32; off; off >>= 1)
        acc += __shfl_down(acc, off, 64);

    __shared__ float s[THREADS / 64];
    const int lane = threadIdx.x & 63;
    const int wid  = threadIdx.x >> 6;
    if (lane == 0) s[wid] = acc;
    __syncthreads();
    if (threadIdx.x == 0) {
        float bsum = s[0] + s[1] + s[2] + s[3];
        atomicAdd(out, bsum * (1.0f / (float)N_ELEM));
    }
}

extern "C" void kernel_launch(void* const* d_in, const int* in_sizes, int n_in,
                              void* d_out, int out_size, void* d_ws, size_t ws_size,
                              hipStream_t stream) {
    const float* pred = (const float*)d_in[0];
    const float* act  = (const float*)d_in[1];
    float* out = (float*)d_out;

    // d_out is poisoned to 0xAA before every timed launch; zero it first.
    hipMemsetAsync(out, 0, sizeof(float), stream);
    metric_loss_kernel<<<BLOCKS, THREADS, 0, stream>>>(pred, act, out);
}